// Round 1
// baseline (4279.955 us; speedup 1.0000x reference)
//
#include <hip/hip_runtime.h>

#define LQ 2048
#define LK 2048
#define BB 16
#define DD 512
#define DKK 64
#define EPSF 1e-9f

__device__ inline float bf2f(unsigned int u16) {
    return __uint_as_float(u16 << 16);
}
__device__ inline unsigned short f2bf(float f) {
    unsigned int u = __float_as_uint(f);
    u += 0x7fffu + ((u >> 16) & 1u);   // round-to-nearest-even
    return (unsigned short)(u >> 16);
}

// y[b][l][dk] = l2norm_dk( x[l,b,:] . W[dk,:] )    x:[L,B,D] f32, W:[DK,D] f32
__global__ __launch_bounds__(256) void k_projqk(const float* __restrict__ x,
                                                const float* __restrict__ W,
                                                float* __restrict__ y)
{
    const int b = blockIdx.y, l0 = blockIdx.x * 16;
    __shared__ float xs[16][512];
    __shared__ float red[4][16][64];
    const int tid = threadIdx.x;

    for (int idx = tid; idx < 16 * 512; idx += 256) {
        int l = idx >> 9, d = idx & 511;
        xs[l][d] = x[(size_t)(l0 + l) * BB * DD + (size_t)b * DD + d];
    }
    __syncthreads();

    const int dk = tid & 63, quarter = tid >> 6;
    float acc[16];
#pragma unroll
    for (int i = 0; i < 16; i++) acc[i] = 0.f;
    const float* wrow = W + (size_t)dk * DD + quarter * 128;
#pragma unroll 4
    for (int dd = 0; dd < 128; dd += 4) {
        float4 w4 = *reinterpret_cast<const float4*>(wrow + dd);
        int d = quarter * 128 + dd;
#pragma unroll
        for (int l = 0; l < 16; l++) {
            float4 x4 = *reinterpret_cast<const float4*>(&xs[l][d]);
            acc[l] += x4.x * w4.x + x4.y * w4.y + x4.z * w4.z + x4.w * w4.w;
        }
    }
#pragma unroll
    for (int l = 0; l < 16; l++) red[quarter][l][dk] = acc[l];
    __syncthreads();

    const int wv_id = tid >> 6;
#pragma unroll
    for (int li = 0; li < 4; ++li) {
        int l = wv_id * 4 + li;
        float v = red[0][l][dk] + red[1][l][dk] + red[2][l][dk] + red[3][l][dk];
        float sq = v * v;
#pragma unroll
        for (int off = 32; off > 0; off >>= 1) sq += __shfl_xor(sq, off, 64);
        float nrm = fmaxf(sqrtf(sq), 1e-12f);
        y[((size_t)b * LQ + (l0 + l)) * DKK + dk] = v / nrm;
    }
}

// wv[b][k][d] = value[k,b,:] . WV[d,:]   (bf16 out)
__global__ __launch_bounds__(256) void k_projv(const float* __restrict__ value,
                                               const float* __restrict__ WV,
                                               unsigned short* __restrict__ wv)
{
    const int b = blockIdx.y, k0 = blockIdx.x * 16;
    __shared__ float xs[16][512];
    const int tid = threadIdx.x;
    for (int idx = tid; idx < 16 * 512; idx += 256) {
        int l = idx >> 9, d = idx & 511;
        xs[l][d] = value[(size_t)(k0 + l) * BB * DD + (size_t)b * DD + d];
    }
    __syncthreads();
#pragma unroll 1
    for (int ph = 0; ph < 2; ++ph) {
        int dcol = tid + 256 * ph;
        const float* wrow = WV + (size_t)dcol * DD;
        float acc[16];
#pragma unroll
        for (int i = 0; i < 16; i++) acc[i] = 0.f;
#pragma unroll 2
        for (int dd = 0; dd < 512; dd += 4) {
            float4 w4 = *reinterpret_cast<const float4*>(wrow + dd);
#pragma unroll
            for (int l = 0; l < 16; l++) {
                float4 x4 = *reinterpret_cast<const float4*>(&xs[l][dd]);
                acc[l] += x4.x * w4.x + x4.y * w4.y + x4.z * w4.z + x4.w * w4.w;
            }
        }
#pragma unroll
        for (int l = 0; l < 16; l++)
            wv[((size_t)b * LK + (k0 + l)) * DD + dcol] = f2bf(acc[l]);
    }
}

// a[b][q] = m_q + log(l_q)  (online softmax row stats over k)
__global__ __launch_bounds__(256) void k_rowstats(const float* __restrict__ wq,
                                                  const float* __restrict__ wk,
                                                  float* __restrict__ aout)
{
    const int b = blockIdx.y, q0 = blockIdx.x * 64;
    __shared__ float buf[64][64];
    __shared__ float redm[4][64], redl[4][64];
    const int tid = threadIdx.x;
    const int ql = tid & 63, kg = tid >> 6;

    float qreg[64];
    const float* qrow = wq + ((size_t)b * LQ + q0 + ql) * DKK;
#pragma unroll
    for (int d = 0; d < 64; d += 4) {
        float4 v = *reinterpret_cast<const float4*>(qrow + d);
        qreg[d] = v.x; qreg[d+1] = v.y; qreg[d+2] = v.z; qreg[d+3] = v.w;
    }
    float rm = -1e30f, rl = 0.f;
#pragma unroll 1
    for (int kt = 0; kt < LK; kt += 64) {
        __syncthreads();
        for (int idx = tid; idx < 64 * 64; idx += 256)
            buf[idx >> 6][idx & 63] = wk[((size_t)b * LK + kt) * DKK + idx];
        __syncthreads();
#pragma unroll 1
        for (int ki = 0; ki < 16; ++ki) {
            int kk = kg * 16 + ki;
            float s = 0.f;
#pragma unroll
            for (int d = 0; d < 64; ++d) s += qreg[d] * buf[kk][d];
            if (s <= rm) { rl += __expf(s - rm); }
            else         { rl = rl * __expf(rm - s) + 1.f; rm = s; }
        }
    }
    redm[kg][ql] = rm; redl[kg][ql] = rl;
    __syncthreads();
    if (tid < 64) {
        float M = fmaxf(fmaxf(redm[0][tid], redm[1][tid]), fmaxf(redm[2][tid], redm[3][tid]));
        float L = redl[0][tid] * __expf(redm[0][tid] - M) + redl[1][tid] * __expf(redm[1][tid] - M)
                + redl[2][tid] * __expf(redm[2][tid] - M) + redl[3][tid] * __expf(redm[3][tid] - M);
        aout[(size_t)b * LQ + q0 + tid] = M + logf(L);
    }
}

// cinv[b][k] = 1/(eps + sum_q exp(s_qk - a_q))
__global__ __launch_bounds__(256) void k_colsum(const float* __restrict__ wq,
                                                const float* __restrict__ wk,
                                                const float* __restrict__ ain,
                                                float* __restrict__ cinv)
{
    const int b = blockIdx.y, k0 = blockIdx.x * 64;
    __shared__ float buf[64][64];
    __shared__ float as[64];
    __shared__ float redc[4][64];
    const int tid = threadIdx.x;
    const int kl = tid & 63, qg = tid >> 6;

    float kreg[64];
    const float* krow = wk + ((size_t)b * LK + k0 + kl) * DKK;
#pragma unroll
    for (int d = 0; d < 64; d += 4) {
        float4 v = *reinterpret_cast<const float4*>(krow + d);
        kreg[d] = v.x; kreg[d+1] = v.y; kreg[d+2] = v.z; kreg[d+3] = v.w;
    }
    float c = 0.f;
#pragma unroll 1
    for (int qt = 0; qt < LQ; qt += 64) {
        __syncthreads();
        for (int idx = tid; idx < 64 * 64; idx += 256)
            buf[idx >> 6][idx & 63] = wq[((size_t)b * LQ + qt) * DKK + idx];
        if (tid < 64) as[tid] = ain[(size_t)b * LQ + qt + tid];
        __syncthreads();
#pragma unroll 1
        for (int qi = 0; qi < 16; ++qi) {
            int qq = qg * 16 + qi;
            float s = 0.f;
#pragma unroll
            for (int d = 0; d < 64; ++d) s += kreg[d] * buf[qq][d];
            c += __expf(s - as[qq]);
        }
    }
    redc[qg][kl] = c;
    __syncthreads();
    if (tid < 64) {
        float C = redc[0][tid] + redc[1][tid] + redc[2][tid] + redc[3][tid];
        cinv[(size_t)b * LK + k0 + tid] = 1.f / (EPSF + C);
    }
}

// t[q,b,:] = query[q,b,:] - sum_k exp(s-a_q)*cinv_k * wv[b][k][:]   (bf16 out)
__global__ __launch_bounds__(256) void k_pv(const float* __restrict__ query,
                                            const float* __restrict__ wq,
                                            const float* __restrict__ wk,
                                            const unsigned short* __restrict__ wv,
                                            const float* __restrict__ ain,
                                            const float* __restrict__ cinv,
                                            unsigned short* __restrict__ tout)
{
    const int b = blockIdx.y, q0 = blockIdx.x * 32;
    __shared__ float wk_s[16][64];
    __shared__ float ps[32][17];
    __shared__ float wv_s[16][512];
    const int tid = threadIdx.x;
    const int ql = tid & 31, dg = tid >> 5;

    float qreg[64];
    const float* qrow = wq + ((size_t)b * LQ + q0 + ql) * DKK;
#pragma unroll
    for (int d = 0; d < 64; d += 4) {
        float4 v = *reinterpret_cast<const float4*>(qrow + d);
        qreg[d] = v.x; qreg[d+1] = v.y; qreg[d+2] = v.z; qreg[d+3] = v.w;
    }
    const float aq = ain[(size_t)b * LQ + q0 + ql];

    float acc[64];
#pragma unroll
    for (int i = 0; i < 64; i++) acc[i] = 0.f;

#pragma unroll 1
    for (int kt = 0; kt < LK; kt += 16) {
        __syncthreads();
        for (int idx = tid; idx < 16 * 64; idx += 256)
            ((float*)wk_s)[idx] = wk[((size_t)b * LK + kt) * DKK + idx];
        {
            const unsigned int* wvsrc = (const unsigned int*)(wv + ((size_t)b * LK + kt) * DD);
            for (int idx = tid; idx < 16 * 256; idx += 256) {
                unsigned int u = wvsrc[idx];
                int r = idx >> 8, d2 = (idx & 255) * 2;
                wv_s[r][d2]     = __uint_as_float(u << 16);
                wv_s[r][d2 + 1] = __uint_as_float(u & 0xffff0000u);
            }
        }
        __syncthreads();
#pragma unroll
        for (int i = 0; i < 2; i++) {
            int kk = (tid >> 5) + 8 * i;
            float s = 0.f;
#pragma unroll
            for (int d = 0; d < 64; ++d) s += qreg[d] * wk_s[kk][d];
            ps[ql][kk] = __expf(s - aq) * cinv[(size_t)b * LK + kt + kk];
        }
        __syncthreads();
#pragma unroll 1
        for (int kk = 0; kk < 16; ++kk) {
            float p = ps[ql][kk];
            const float* row = &wv_s[kk][dg * 64];
#pragma unroll
            for (int e = 0; e < 64; ++e) acc[e] += p * row[e];
        }
    }

    const size_t rowbase = ((size_t)(q0 + ql) * BB + b) * DD + dg * 64;
#pragma unroll
    for (int e = 0; e < 64; e += 4) {
        float4 qv = *reinterpret_cast<const float4*>(&query[rowbase + e]);
        ushort4 pk;
        pk.x = f2bf(qv.x - acc[e]);
        pk.y = f2bf(qv.y - acc[e + 1]);
        pk.z = f2bf(qv.z - acc[e + 2]);
        pk.w = f2bf(qv.w - acc[e + 3]);
        *reinterpret_cast<ushort4*>(&tout[rowbase + e]) = pk;
    }
}

// out[row][d] = relu( t[row,:] . Wt[d,:] )   rows = q*B+b, f32 out
__global__ __launch_bounds__(256) void k_final(const unsigned short* __restrict__ t,
                                               const float* __restrict__ Wt,
                                               float* __restrict__ out)
{
    const int r0 = blockIdx.x * 16;
    __shared__ float ts[16][512];
    const int tid = threadIdx.x;
    const unsigned int* tsrc = (const unsigned int*)(t + (size_t)r0 * DD);
    for (int idx = tid; idx < 16 * 256; idx += 256) {
        unsigned int u = tsrc[idx];
        int r = idx >> 8, d = (idx & 255) * 2;
        ts[r][d]     = __uint_as_float(u << 16);
        ts[r][d + 1] = __uint_as_float(u & 0xffff0000u);
    }
    __syncthreads();
#pragma unroll 1
    for (int ph = 0; ph < 2; ++ph) {
        int dcol = tid + 256 * ph;
        const float* wrow = Wt + (size_t)dcol * DD;
        float acc[16];
#pragma unroll
        for (int i = 0; i < 16; i++) acc[i] = 0.f;
#pragma unroll 2
        for (int dd = 0; dd < 512; dd += 4) {
            float4 w4 = *reinterpret_cast<const float4*>(wrow + dd);
#pragma unroll
            for (int r = 0; r < 16; r++) {
                float4 x4 = *reinterpret_cast<const float4*>(&ts[r][dd]);
                acc[r] += x4.x * w4.x + x4.y * w4.y + x4.z * w4.z + x4.w * w4.w;
            }
        }
#pragma unroll
        for (int r = 0; r < 16; r++)
            out[(size_t)(r0 + r) * DD + dcol] = fmaxf(acc[r], 0.f);
    }
}

extern "C" void kernel_launch(void* const* d_in, const int* in_sizes, int n_in,
                              void* d_out, int out_size, void* d_ws, size_t ws_size,
                              hipStream_t stream)
{
    const float* query = (const float*)d_in[0];
    const float* key   = (const float*)d_in[1];
    const float* value = (const float*)d_in[2];
    const float* WK    = (const float*)d_in[3];
    const float* WQ    = (const float*)d_in[4];
    const float* WV    = (const float*)d_in[5];
    const float* Wt    = (const float*)d_in[6];
    float* out = (float*)d_out;

    char* ws = (char*)d_ws;
    float*          wq = (float*)(ws);                          //  8 MB  [B][LQ][DK] f32
    float*          wk = (float*)(ws + 8388608);                //  8 MB  [B][LK][DK] f32
    unsigned short* wv = (unsigned short*)(ws + 16777216);      // 32 MB  [B][LK][D] bf16
    float*          a  = (float*)(ws + 50331648);               // 128 KB [B][LQ] f32
    float*          ci = (float*)(ws + 50462720);               // 128 KB [B][LK] f32
    unsigned short* t  = (unsigned short*)(ws + 50593792);      // 32 MB  [LQ][B][D] bf16

    k_projqk<<<dim3(LQ / 16, BB), 256, 0, stream>>>(query, WQ, wq);
    k_projqk<<<dim3(LK / 16, BB), 256, 0, stream>>>(key, WK, wk);
    k_projv <<<dim3(LK / 16, BB), 256, 0, stream>>>(value, WV, wv);
    k_rowstats<<<dim3(LQ / 64, BB), 256, 0, stream>>>(wq, wk, a);
    k_colsum<<<dim3(LK / 64, BB), 256, 0, stream>>>(wq, wk, a, ci);
    k_pv   <<<dim3(LQ / 32, BB), 256, 0, stream>>>(query, wq, wk, wv, a, ci, t);
    k_final<<<2048, 256, 0, stream>>>(t, Wt, out);
}

// Round 2
// 725.100 us; speedup vs baseline: 5.9026x; 5.9026x over previous
//
#include <hip/hip_runtime.h>

#define LQ 2048
#define LK 2048
#define BB 16
#define DD 512
#define DKK 64
#define EPSF 1e-9f

typedef unsigned short u16;
typedef __attribute__((ext_vector_type(8))) short bf16x8;
typedef __attribute__((ext_vector_type(4))) float f32x4;
#define MFMA16(a, b, c) __builtin_amdgcn_mfma_f32_16x16x32_bf16(a, b, c, 0, 0, 0)

__device__ inline u16 f2bf(float f) {
    unsigned int u = __float_as_uint(f);
    u += 0x7fffu + ((u >> 16) & 1u);   // RNE
    return (u16)(u >> 16);
}
__device__ inline bf16x8 cvt8(float4 a, float4 b) {
    bf16x8 r;
    r[0] = (short)f2bf(a.x); r[1] = (short)f2bf(a.y); r[2] = (short)f2bf(a.z); r[3] = (short)f2bf(a.w);
    r[4] = (short)f2bf(b.x); r[5] = (short)f2bf(b.y); r[6] = (short)f2bf(b.z); r[7] = (short)f2bf(b.w);
    return r;
}

// f32 -> bf16 bulk convert (weights)
__global__ __launch_bounds__(256) void k_cvt(const float* __restrict__ src, u16* __restrict__ dst, int n) {
    int i = (blockIdx.x * 256 + threadIdx.x) * 4;
    if (i < n) {
        float4 v = *reinterpret_cast<const float4*>(src + i);
        *reinterpret_cast<ushort4*>(dst + i) = make_ushort4(f2bf(v.x), f2bf(v.y), f2bf(v.z), f2bf(v.w));
    }
}

// y[b][l][dk] = l2norm( x[l,b,:] @ Wb[dk,:] )   x:[L,B,D] f32, Wb:[DK=64][D] bf16, y bf16
__global__ __launch_bounds__(256) void k_projqk(const float* __restrict__ x, const u16* __restrict__ Wb,
                                                u16* __restrict__ y)
{
    const int b = blockIdx.y, r0 = blockIdx.x * 128;
    const int tid = threadIdx.x, wave = tid >> 6, lane = tid & 63, l15 = lane & 15, g = lane >> 4;
    const int rw = r0 + wave * 32;
    f32x4 z = {0.f, 0.f, 0.f, 0.f};
    f32x4 acc[2][4];
#pragma unroll
    for (int m = 0; m < 2; m++)
#pragma unroll
        for (int nf = 0; nf < 4; nf++) acc[m][nf] = z;

    for (int kt = 0; kt < DD; kt += 32) {
        bf16x8 af[2];
#pragma unroll
        for (int m = 0; m < 2; m++) {
            const float* p = x + ((size_t)(rw + 16 * m + l15) * BB + b) * DD + kt + g * 8;
            af[m] = cvt8(*reinterpret_cast<const float4*>(p), *reinterpret_cast<const float4*>(p + 4));
        }
#pragma unroll
        for (int nf = 0; nf < 4; nf++) {
            bf16x8 bf_ = *reinterpret_cast<const bf16x8*>(Wb + (size_t)(nf * 16 + l15) * DD + kt + g * 8);
            acc[0][nf] = MFMA16(af[0], bf_, acc[0][nf]);
            acc[1][nf] = MFMA16(af[1], bf_, acc[1][nf]);
        }
    }
#pragma unroll
    for (int m = 0; m < 2; m++) {
        float rn[4];
#pragma unroll
        for (int j = 0; j < 4; j++) {
            float t2 = acc[m][0][j] * acc[m][0][j] + acc[m][1][j] * acc[m][1][j]
                     + acc[m][2][j] * acc[m][2][j] + acc[m][3][j] * acc[m][3][j];
            t2 += __shfl_xor(t2, 1, 64);
            t2 += __shfl_xor(t2, 2, 64);
            t2 += __shfl_xor(t2, 4, 64);
            t2 += __shfl_xor(t2, 8, 64);
            rn[j] = 1.f / fmaxf(sqrtf(t2), 1e-12f);
        }
#pragma unroll
        for (int nf = 0; nf < 4; nf++)
#pragma unroll
            for (int j = 0; j < 4; j++) {
                int q = rw + 16 * m + g * 4 + j;
                y[((size_t)b * LQ + q) * DKK + nf * 16 + l15] = f2bf(acc[m][nf][j] * rn[j]);
            }
    }
}

// wvT[b][d][k] = value[k,b,:] @ WVb[d,:]    value f32, WVb bf16 [512][512], wvT bf16
__global__ __launch_bounds__(256) void k_projv(const float* __restrict__ value, const u16* __restrict__ WVb,
                                               u16* __restrict__ wvT)
{
    const int b = blockIdx.y, k0 = blockIdx.x * 32;
    const int tid = threadIdx.x, wave = tid >> 6, lane = tid & 63, l15 = lane & 15, g = lane >> 4;
    f32x4 z = {0.f, 0.f, 0.f, 0.f};
    f32x4 acc[2][8];
#pragma unroll
    for (int m = 0; m < 2; m++)
#pragma unroll
        for (int nf = 0; nf < 8; nf++) acc[m][nf] = z;

    for (int kt = 0; kt < DD; kt += 32) {
        bf16x8 af[2];
#pragma unroll
        for (int m = 0; m < 2; m++) {
            const float* p = value + ((size_t)(k0 + 16 * m + l15) * BB + b) * DD + kt + g * 8;
            af[m] = cvt8(*reinterpret_cast<const float4*>(p), *reinterpret_cast<const float4*>(p + 4));
        }
#pragma unroll
        for (int nf = 0; nf < 8; nf++) {
            bf16x8 bf_ = *reinterpret_cast<const bf16x8*>(WVb + (size_t)(wave * 128 + nf * 16 + l15) * DD + kt + g * 8);
            acc[0][nf] = MFMA16(af[0], bf_, acc[0][nf]);
            acc[1][nf] = MFMA16(af[1], bf_, acc[1][nf]);
        }
    }
#pragma unroll
    for (int m = 0; m < 2; m++)
#pragma unroll
        for (int nf = 0; nf < 8; nf++) {
            int d = wave * 128 + nf * 16 + l15;
            size_t base = ((size_t)b * DD + d) * LK + k0 + 16 * m + g * 4;
            *reinterpret_cast<ushort4*>(wvT + base) =
                make_ushort4(f2bf(acc[m][nf][0]), f2bf(acc[m][nf][1]), f2bf(acc[m][nf][2]), f2bf(acc[m][nf][3]));
        }
}

// out[row] = 1/(eps + sum_cols exp(s[row][col]) * w[col]),  s = A @ B^T over dk=64
// A,B: [b][2048][64] bf16.  wcol nullptr -> 1.
__global__ __launch_bounds__(256) void k_expsum(const u16* __restrict__ A, const u16* __restrict__ Bm,
                                                const float* __restrict__ wcol, float* __restrict__ outv,
                                                float eps)
{
    const int b = blockIdx.y, r0 = blockIdx.x * 32;
    const int tid = threadIdx.x, wave = tid >> 6, lane = tid & 63, l15 = lane & 15, g = lane >> 4;
    __shared__ float red[4][32];
    f32x4 z = {0.f, 0.f, 0.f, 0.f};

    bf16x8 af[2][2];
#pragma unroll
    for (int m = 0; m < 2; m++)
#pragma unroll
        for (int kk = 0; kk < 2; kk++)
            af[m][kk] = *reinterpret_cast<const bf16x8*>(A + ((size_t)b * LK + r0 + 16 * m + l15) * DKK + kk * 32 + g * 8);

    float acc2[2][4] = {{0.f, 0.f, 0.f, 0.f}, {0.f, 0.f, 0.f, 0.f}};

    for (int ti = 0; ti < 16; ti++) {
        int ktb = (wave + 4 * ti) * 32;
#pragma unroll
        for (int n = 0; n < 2; n++) {
            const u16* brow = Bm + ((size_t)b * LK + ktb + 16 * n + l15) * DKK;
            bf16x8 b0 = *reinterpret_cast<const bf16x8*>(brow + g * 8);
            bf16x8 b1 = *reinterpret_cast<const bf16x8*>(brow + 32 + g * 8);
            float w = 1.f;
            if (wcol) w = wcol[(size_t)b * LK + ktb + 16 * n + l15];
#pragma unroll
            for (int m = 0; m < 2; m++) {
                f32x4 s = z;
                s = MFMA16(af[m][0], b0, s);
                s = MFMA16(af[m][1], b1, s);
#pragma unroll
                for (int j = 0; j < 4; j++) acc2[m][j] += __expf(s[j]) * w;
            }
        }
    }
#pragma unroll
    for (int m = 0; m < 2; m++)
#pragma unroll
        for (int j = 0; j < 4; j++) {
            float v = acc2[m][j];
            v += __shfl_xor(v, 1, 64);
            v += __shfl_xor(v, 2, 64);
            v += __shfl_xor(v, 4, 64);
            v += __shfl_xor(v, 8, 64);
            if (l15 == 0) red[wave][16 * m + g * 4 + j] = v;
        }
    __syncthreads();
    if (tid < 32) {
        float s = red[0][tid] + red[1][tid] + red[2][tid] + red[3][tid];
        outv[(size_t)b * LK + r0 + tid] = 1.f / (eps + s);
    }
}

// t[q,b,:] = query[q,b,:] - sum_k exp(s_qk)*R_q*cinv_k * wv[k,:]
__global__ __launch_bounds__(256) void k_pv(const float* __restrict__ query, const u16* __restrict__ wqb,
                                            const u16* __restrict__ wkb, const u16* __restrict__ wvT,
                                            const float* __restrict__ Rq, const float* __restrict__ ci,
                                            u16* __restrict__ tout)
{
    const int b = blockIdx.y, q0 = blockIdx.x * 32;
    const int tid = threadIdx.x, wave = tid >> 6, lane = tid & 63, l15 = lane & 15, g = lane >> 4;
    const int sm = wave >> 1, sn = wave & 1;
    __shared__ __align__(16) u16 p_lds[2][32][40];   // padded rows: 80B -> conflict-free b128
    f32x4 z = {0.f, 0.f, 0.f, 0.f};

    const u16* qrow = wqb + ((size_t)b * LQ + q0 + 16 * sm + l15) * DKK;
    bf16x8 qf0 = *reinterpret_cast<const bf16x8*>(qrow + g * 8);
    bf16x8 qf1 = *reinterpret_cast<const bf16x8*>(qrow + 32 + g * 8);
    float Rr[4];
#pragma unroll
    for (int j = 0; j < 4; j++) Rr[j] = Rq[(size_t)b * LQ + q0 + 16 * sm + g * 4 + j];

    f32x4 acc[2][8];
#pragma unroll
    for (int m = 0; m < 2; m++)
#pragma unroll
        for (int nf = 0; nf < 8; nf++) acc[m][nf] = z;

    int buf = 0;
    for (int kt = 0; kt < LK; kt += 32) {
        const u16* krow = wkb + ((size_t)b * LK + kt + 16 * sn + l15) * DKK;
        bf16x8 kf0 = *reinterpret_cast<const bf16x8*>(krow + g * 8);
        bf16x8 kf1 = *reinterpret_cast<const bf16x8*>(krow + 32 + g * 8);
        f32x4 s = z;
        s = MFMA16(qf0, kf0, s);
        s = MFMA16(qf1, kf1, s);
        float civ = ci[(size_t)b * LK + kt + 16 * sn + l15];
#pragma unroll
        for (int j = 0; j < 4; j++)
            p_lds[buf][16 * sm + g * 4 + j][16 * sn + l15] = f2bf(__expf(s[j]) * Rr[j] * civ);
        __syncthreads();
        bf16x8 pa0 = *reinterpret_cast<const bf16x8*>(&p_lds[buf][l15][g * 8]);
        bf16x8 pa1 = *reinterpret_cast<const bf16x8*>(&p_lds[buf][16 + l15][g * 8]);
#pragma unroll
        for (int nf = 0; nf < 8; nf++) {
            bf16x8 bv = *reinterpret_cast<const bf16x8*>(
                wvT + ((size_t)b * DD + wave * 128 + nf * 16 + l15) * LK + kt + g * 8);
            acc[0][nf] = MFMA16(pa0, bv, acc[0][nf]);
            acc[1][nf] = MFMA16(pa1, bv, acc[1][nf]);
        }
        buf ^= 1;
    }
#pragma unroll
    for (int m = 0; m < 2; m++)
#pragma unroll
        for (int nf = 0; nf < 8; nf++)
#pragma unroll
            for (int j = 0; j < 4; j++) {
                int q = q0 + 16 * m + g * 4 + j;
                int d = wave * 128 + nf * 16 + l15;
                size_t idx = ((size_t)q * BB + b) * DD + d;
                tout[idx] = f2bf(query[idx] - acc[m][nf][j]);
            }
}

// out[r][n] = relu( t[r,:] @ Wtb[n,:] )    t bf16 [32768][512], Wtb bf16 [512][512], out f32
__global__ __launch_bounds__(256) void k_final(const u16* __restrict__ t, const u16* __restrict__ Wtb,
                                               float* __restrict__ out)
{
    const int r0 = blockIdx.x * 32;
    const int tid = threadIdx.x, wave = tid >> 6, lane = tid & 63, l15 = lane & 15, g = lane >> 4;
    f32x4 z = {0.f, 0.f, 0.f, 0.f};
    f32x4 acc[2][8];
#pragma unroll
    for (int m = 0; m < 2; m++)
#pragma unroll
        for (int nf = 0; nf < 8; nf++) acc[m][nf] = z;

    for (int kt = 0; kt < DD; kt += 32) {
        bf16x8 a0 = *reinterpret_cast<const bf16x8*>(t + (size_t)(r0 + l15) * DD + kt + g * 8);
        bf16x8 a1 = *reinterpret_cast<const bf16x8*>(t + (size_t)(r0 + 16 + l15) * DD + kt + g * 8);
#pragma unroll
        for (int nf = 0; nf < 8; nf++) {
            bf16x8 bw = *reinterpret_cast<const bf16x8*>(Wtb + (size_t)(wave * 128 + nf * 16 + l15) * DD + kt + g * 8);
            acc[0][nf] = MFMA16(a0, bw, acc[0][nf]);
            acc[1][nf] = MFMA16(a1, bw, acc[1][nf]);
        }
    }
#pragma unroll
    for (int m = 0; m < 2; m++)
#pragma unroll
        for (int nf = 0; nf < 8; nf++)
#pragma unroll
            for (int j = 0; j < 4; j++)
                out[(size_t)(r0 + 16 * m + g * 4 + j) * DD + wave * 128 + nf * 16 + l15] =
                    fmaxf(acc[m][nf][j], 0.f);
}

extern "C" void kernel_launch(void* const* d_in, const int* in_sizes, int n_in,
                              void* d_out, int out_size, void* d_ws, size_t ws_size,
                              hipStream_t stream)
{
    const float* query = (const float*)d_in[0];
    const float* key   = (const float*)d_in[1];
    const float* value = (const float*)d_in[2];
    const float* WK    = (const float*)d_in[3];
    const float* WQ    = (const float*)d_in[4];
    const float* WV    = (const float*)d_in[5];
    const float* Wt    = (const float*)d_in[6];
    float* out = (float*)d_out;

    char* ws = (char*)d_ws;
    u16*   wqb = (u16*)(ws);                                   //  4 MB [B][LQ][64] bf16
    u16*   wkb = (u16*)(ws + (4u << 20));                      //  4 MB [B][LK][64] bf16
    u16*   wvT = (u16*)(ws + (8u << 20));                      // 32 MB [B][512][LK] bf16
    u16*   t   = (u16*)(ws + (40u << 20));                     // 32 MB [LQ][B][512] bf16
    float* Rq  = (float*)(ws + (72u << 20));                   // 128 KB [B][LQ] f32
    float* ci  = (float*)(ws + (72u << 20) + (128u << 10));    // 128 KB [B][LK] f32
    u16*   WQb = (u16*)(ws + (72u << 20) + (256u << 10));      // 64 KB
    u16*   WKb = (u16*)(ws + (72u << 20) + (320u << 10));      // 64 KB
    u16*   WVb = (u16*)(ws + (72u << 20) + (384u << 10));      // 512 KB
    u16*   Wtb = (u16*)(ws + (72u << 20) + (896u << 10));      // 512 KB

    k_cvt<<<32, 256, 0, stream>>>(WQ, WQb, DKK * DD);
    k_cvt<<<32, 256, 0, stream>>>(WK, WKb, DKK * DD);
    k_cvt<<<256, 256, 0, stream>>>(WV, WVb, DD * DD);
    k_cvt<<<256, 256, 0, stream>>>(Wt, Wtb, DD * DD);

    k_projqk<<<dim3(LQ / 128, BB), 256, 0, stream>>>(query, WQb, wqb);
    k_projqk<<<dim3(LK / 128, BB), 256, 0, stream>>>(key, WKb, wkb);
    k_projv <<<dim3(LK / 32, BB), 256, 0, stream>>>(value, WVb, wvT);

    k_expsum<<<dim3(LQ / 32, BB), 256, 0, stream>>>(wqb, wkb, nullptr, Rq, 0.f);
    k_expsum<<<dim3(LK / 32, BB), 256, 0, stream>>>(wkb, wqb, Rq, ci, EPSF);

    k_pv<<<dim3(LQ / 32, BB), 256, 0, stream>>>(query, wqb, wkb, wvT, Rq, ci, t);
    k_final<<<1024, 256, 0, stream>>>(t, Wtb, out);
}

// Round 3
// 548.716 us; speedup vs baseline: 7.7999x; 1.3214x over previous
//
#include <hip/hip_runtime.h>

#define LQ 2048
#define LK 2048
#define BB 16
#define DD 512
#define DKK 64
#define EPSF 1e-9f

typedef unsigned short u16;
typedef __attribute__((ext_vector_type(8))) short bf16x8;
typedef __attribute__((ext_vector_type(4))) float f32x4;
#define MFMA16(a, b, c) __builtin_amdgcn_mfma_f32_16x16x32_bf16(a, b, c, 0, 0, 0)

__device__ inline u16 f2bf(float f) {
    unsigned int u = __float_as_uint(f);
    u += 0x7fffu + ((u >> 16) & 1u);   // RNE
    return (u16)(u >> 16);
}
__device__ inline bf16x8 cvt8(float4 a, float4 b) {
    bf16x8 r;
    r[0] = (short)f2bf(a.x); r[1] = (short)f2bf(a.y); r[2] = (short)f2bf(a.z); r[3] = (short)f2bf(a.w);
    r[4] = (short)f2bf(b.x); r[5] = (short)f2bf(b.y); r[6] = (short)f2bf(b.z); r[7] = (short)f2bf(b.w);
    return r;
}

// f32 -> bf16 bulk convert (weights)
__global__ __launch_bounds__(256) void k_cvt(const float* __restrict__ src, u16* __restrict__ dst, int n) {
    int i = (blockIdx.x * 256 + threadIdx.x) * 4;
    if (i < n) {
        float4 v = *reinterpret_cast<const float4*>(src + i);
        *reinterpret_cast<ushort4*>(dst + i) = make_ushort4(f2bf(v.x), f2bf(v.y), f2bf(v.z), f2bf(v.w));
    }
}

// y[b][l][dk] = l2norm( x[l,b,:] @ Wb[dk,:] )   x:[L,B,D] f32, Wb:[64][512] bf16
__global__ __launch_bounds__(256) void k_projqk(const float* __restrict__ x, const u16* __restrict__ Wb,
                                                u16* __restrict__ y)
{
    const int b = blockIdx.y, r0 = blockIdx.x * 128;
    const int tid = threadIdx.x, wave = tid >> 6, lane = tid & 63, l15 = lane & 15, g = lane >> 4;
    const int rw = r0 + wave * 32;
    f32x4 z = {0.f, 0.f, 0.f, 0.f};
    f32x4 acc[2][4];
#pragma unroll
    for (int m = 0; m < 2; m++)
#pragma unroll
        for (int nf = 0; nf < 4; nf++) acc[m][nf] = z;

    for (int kt = 0; kt < DD; kt += 32) {
        bf16x8 af[2];
#pragma unroll
        for (int m = 0; m < 2; m++) {
            const float* p = x + ((size_t)(rw + 16 * m + l15) * BB + b) * DD + kt + g * 8;
            af[m] = cvt8(*reinterpret_cast<const float4*>(p), *reinterpret_cast<const float4*>(p + 4));
        }
#pragma unroll
        for (int nf = 0; nf < 4; nf++) {
            bf16x8 bf_ = *reinterpret_cast<const bf16x8*>(Wb + (size_t)(nf * 16 + l15) * DD + kt + g * 8);
            acc[0][nf] = MFMA16(af[0], bf_, acc[0][nf]);
            acc[1][nf] = MFMA16(af[1], bf_, acc[1][nf]);
        }
    }
#pragma unroll
    for (int m = 0; m < 2; m++) {
        float rn[4];
#pragma unroll
        for (int j = 0; j < 4; j++) {
            float t2 = acc[m][0][j] * acc[m][0][j] + acc[m][1][j] * acc[m][1][j]
                     + acc[m][2][j] * acc[m][2][j] + acc[m][3][j] * acc[m][3][j];
            t2 += __shfl_xor(t2, 1, 64);
            t2 += __shfl_xor(t2, 2, 64);
            t2 += __shfl_xor(t2, 4, 64);
            t2 += __shfl_xor(t2, 8, 64);
            rn[j] = 1.f / fmaxf(sqrtf(t2), 1e-12f);
        }
#pragma unroll
        for (int nf = 0; nf < 4; nf++)
#pragma unroll
            for (int j = 0; j < 4; j++) {
                int q = rw + 16 * m + g * 4 + j;
                y[((size_t)b * LQ + q) * DKK + nf * 16 + l15] = f2bf(acc[m][nf][j] * rn[j]);
            }
    }
}

// wvT[b][d][k] = value[k,b,:] @ WVb[d,:]   BM=128 k-rows, BN=256 d, LDS-staged A cvt
__global__ __launch_bounds__(512) void k_projv(const float* __restrict__ value, const u16* __restrict__ WVb,
                                               u16* __restrict__ wvT)
{
    const int b = blockIdx.z, k0 = blockIdx.x * 128, n0 = blockIdx.y * 256;
    const int tid = threadIdx.x, lane = tid & 63, l15 = lane & 15, g = lane >> 4;
    const int wave = tid >> 6, qg = wave >> 2, dg = wave & 3;
    __shared__ __align__(16) u16 A[2][128][40];
    f32x4 z = {0.f, 0.f, 0.f, 0.f};
    f32x4 acc[4][4];
#pragma unroll
    for (int m = 0; m < 4; m++)
#pragma unroll
        for (int nf = 0; nf < 4; nf++) acc[m][nf] = z;

    const int sr = tid >> 2, sc = (tid & 3) * 8;
    {
        const float* p = value + ((size_t)(k0 + sr) * BB + b) * DD + sc;
        *reinterpret_cast<bf16x8*>(&A[0][sr][sc]) =
            cvt8(*reinterpret_cast<const float4*>(p), *reinterpret_cast<const float4*>(p + 4));
    }
    __syncthreads();
    int buf = 0;
    for (int kt = 0; kt < DD; kt += 32) {
        if (kt + 32 < DD) {
            const float* p = value + ((size_t)(k0 + sr) * BB + b) * DD + kt + 32 + sc;
            *reinterpret_cast<bf16x8*>(&A[buf ^ 1][sr][sc]) =
                cvt8(*reinterpret_cast<const float4*>(p), *reinterpret_cast<const float4*>(p + 4));
        }
        bf16x8 af[4];
#pragma unroll
        for (int m = 0; m < 4; m++)
            af[m] = *reinterpret_cast<const bf16x8*>(&A[buf][qg * 64 + m * 16 + l15][g * 8]);
#pragma unroll
        for (int nf = 0; nf < 4; nf++) {
            bf16x8 bw = *reinterpret_cast<const bf16x8*>(WVb + (size_t)(n0 + dg * 64 + nf * 16 + l15) * DD + kt + g * 8);
#pragma unroll
            for (int m = 0; m < 4; m++) acc[m][nf] = MFMA16(af[m], bw, acc[m][nf]);
        }
        __syncthreads();
        buf ^= 1;
    }
#pragma unroll
    for (int m = 0; m < 4; m++)
#pragma unroll
        for (int nf = 0; nf < 4; nf++) {
            int d = n0 + dg * 64 + nf * 16 + l15;
            size_t base = ((size_t)b * DD + d) * LK + k0 + qg * 64 + m * 16 + g * 4;
            *reinterpret_cast<ushort4*>(wvT + base) =
                make_ushort4(f2bf(acc[m][nf][0]), f2bf(acc[m][nf][1]), f2bf(acc[m][nf][2]), f2bf(acc[m][nf][3]));
        }
}

// outv[row] = 1/(eps + sum_cols exp(s)*w[col]),  s = A @ B^T over dk=64. BM=64, wave owns 16 rows.
__global__ __launch_bounds__(256) void k_expsum(const u16* __restrict__ A, const u16* __restrict__ Bm,
                                                const float* __restrict__ wcol, float* __restrict__ outv,
                                                float eps)
{
    const int b = blockIdx.y, r0 = blockIdx.x * 64;
    const int tid = threadIdx.x, wave = tid >> 6, lane = tid & 63, l15 = lane & 15, g = lane >> 4;
    f32x4 z = {0.f, 0.f, 0.f, 0.f};

    const u16* arow = A + ((size_t)b * LK + r0 + wave * 16 + l15) * DKK;
    bf16x8 af0 = *reinterpret_cast<const bf16x8*>(arow + g * 8);
    bf16x8 af1 = *reinterpret_cast<const bf16x8*>(arow + 32 + g * 8);
    float acc[4] = {0.f, 0.f, 0.f, 0.f};

    for (int ct = 0; ct < LK; ct += 64) {
#pragma unroll
        for (int n = 0; n < 4; n++) {
            int col = ct + n * 16;
            const u16* brow = Bm + ((size_t)b * LK + col + l15) * DKK;
            bf16x8 b0 = *reinterpret_cast<const bf16x8*>(brow + g * 8);
            bf16x8 b1 = *reinterpret_cast<const bf16x8*>(brow + 32 + g * 8);
            float w = wcol ? wcol[(size_t)b * LK + col + l15] : 1.f;
            f32x4 s = z;
            s = MFMA16(af0, b0, s);
            s = MFMA16(af1, b1, s);
#pragma unroll
            for (int j = 0; j < 4; j++) acc[j] += __expf(s[j]) * w;
        }
    }
#pragma unroll
    for (int j = 0; j < 4; j++) {
        float v = acc[j];
        v += __shfl_xor(v, 1, 64);
        v += __shfl_xor(v, 2, 64);
        v += __shfl_xor(v, 4, 64);
        v += __shfl_xor(v, 8, 64);
        if (l15 == 0) outv[(size_t)b * LK + r0 + wave * 16 + g * 4 + j] = 1.f / (eps + v);
    }
}

// t[q,b,:] = query - sum_k exp(s)*Rq*ci * wv[k,:]   BM=128 q, BN=256 d, BK=64, P in LDS dbuf
__global__ __launch_bounds__(512) void k_pv(const float* __restrict__ query, const u16* __restrict__ wqb,
                                            const u16* __restrict__ wkb, const u16* __restrict__ wvT,
                                            const float* __restrict__ Rq, const float* __restrict__ ci,
                                            u16* __restrict__ tout)
{
    // XCD-pinned swizzle: XCD = i%8 hosts b in {i%8, i%8+8} -> wvT[b] (2x2MB) stays in its 4MB L2
    const int i = blockIdx.x;
    const int b = (i & 7) + 8 * ((i >> 3) & 1);
    const int rest = i >> 4;
    const int q0 = (rest & 15) * 128, n0 = (rest >> 4) * 256;
    const int tid = threadIdx.x, wave = tid >> 6, lane = tid & 63, l15 = lane & 15, g = lane >> 4;
    const int qg = wave >> 2, dg = wave & 3;
    __shared__ __align__(16) u16 P[2][128][72];
    f32x4 z = {0.f, 0.f, 0.f, 0.f};

    const u16* qrow = wqb + ((size_t)b * LQ + q0 + wave * 16 + l15) * DKK;
    bf16x8 qf0 = *reinterpret_cast<const bf16x8*>(qrow + g * 8);
    bf16x8 qf1 = *reinterpret_cast<const bf16x8*>(qrow + 32 + g * 8);
    float Rr[4];
#pragma unroll
    for (int j = 0; j < 4; j++) Rr[j] = Rq[(size_t)b * LQ + q0 + wave * 16 + g * 4 + j];

    f32x4 acc[4][4];
#pragma unroll
    for (int m = 0; m < 4; m++)
#pragma unroll
        for (int nf = 0; nf < 4; nf++) acc[m][nf] = z;

    auto fill = [&](int bufw, int kt) {
#pragma unroll
        for (int n = 0; n < 4; n++) {
            const u16* krow = wkb + ((size_t)b * LK + kt + n * 16 + l15) * DKK;
            bf16x8 kf0 = *reinterpret_cast<const bf16x8*>(krow + g * 8);
            bf16x8 kf1 = *reinterpret_cast<const bf16x8*>(krow + 32 + g * 8);
            float civ = ci[(size_t)b * LK + kt + n * 16 + l15];
            f32x4 s = z;
            s = MFMA16(qf0, kf0, s);
            s = MFMA16(qf1, kf1, s);
#pragma unroll
            for (int j = 0; j < 4; j++)
                P[bufw][wave * 16 + g * 4 + j][n * 16 + l15] = f2bf(__expf(s[j]) * Rr[j] * civ);
        }
    };

    fill(0, 0);
    __syncthreads();
    int buf = 0;
    for (int kt = 0; kt < LK; kt += 64) {
        bf16x8 pa[4][2];
#pragma unroll
        for (int m = 0; m < 4; m++)
#pragma unroll
            for (int kk = 0; kk < 2; kk++)
                pa[m][kk] = *reinterpret_cast<const bf16x8*>(&P[buf][qg * 64 + m * 16 + l15][kk * 32 + g * 8]);

        if (kt + 64 < LK) fill(buf ^ 1, kt + 64);

#pragma unroll
        for (int nf = 0; nf < 4; nf++) {
            const u16* vrow = wvT + ((size_t)b * DD + n0 + dg * 64 + nf * 16 + l15) * LK + kt;
            bf16x8 bv0 = *reinterpret_cast<const bf16x8*>(vrow + g * 8);
            bf16x8 bv1 = *reinterpret_cast<const bf16x8*>(vrow + 32 + g * 8);
#pragma unroll
            for (int m = 0; m < 4; m++) {
                acc[m][nf] = MFMA16(pa[m][0], bv0, acc[m][nf]);
                acc[m][nf] = MFMA16(pa[m][1], bv1, acc[m][nf]);
            }
        }
        __syncthreads();
        buf ^= 1;
    }
#pragma unroll
    for (int m = 0; m < 4; m++)
#pragma unroll
        for (int nf = 0; nf < 4; nf++)
#pragma unroll
            for (int j = 0; j < 4; j++) {
                int q = q0 + qg * 64 + m * 16 + g * 4 + j;
                int d = n0 + dg * 64 + nf * 16 + l15;
                size_t idx = ((size_t)q * BB + b) * DD + d;
                tout[idx] = f2bf(query[idx] - acc[m][nf][j]);
            }
}

// out[r][n] = relu( t[r,:] @ Wtb[n,:] )   BM=128, BN=256
__global__ __launch_bounds__(512) void k_final(const u16* __restrict__ t, const u16* __restrict__ Wtb,
                                               float* __restrict__ out)
{
    const int r0 = blockIdx.x * 128, n0 = blockIdx.y * 256;
    const int tid = threadIdx.x, wave = tid >> 6, lane = tid & 63, l15 = lane & 15, g = lane >> 4;
    const int qg = wave >> 2, dg = wave & 3;
    f32x4 z = {0.f, 0.f, 0.f, 0.f};
    f32x4 acc[4][4];
#pragma unroll
    for (int m = 0; m < 4; m++)
#pragma unroll
        for (int nf = 0; nf < 4; nf++) acc[m][nf] = z;

    for (int kt = 0; kt < DD; kt += 32) {
        bf16x8 af[4];
#pragma unroll
        for (int m = 0; m < 4; m++)
            af[m] = *reinterpret_cast<const bf16x8*>(t + (size_t)(r0 + qg * 64 + m * 16 + l15) * DD + kt + g * 8);
#pragma unroll
        for (int nf = 0; nf < 4; nf++) {
            bf16x8 bw = *reinterpret_cast<const bf16x8*>(Wtb + (size_t)(n0 + dg * 64 + nf * 16 + l15) * DD + kt + g * 8);
#pragma unroll
            for (int m = 0; m < 4; m++) acc[m][nf] = MFMA16(af[m], bw, acc[m][nf]);
        }
    }
#pragma unroll
    for (int m = 0; m < 4; m++)
#pragma unroll
        for (int nf = 0; nf < 4; nf++)
#pragma unroll
            for (int j = 0; j < 4; j++)
                out[(size_t)(r0 + qg * 64 + m * 16 + g * 4 + j) * DD + n0 + dg * 64 + nf * 16 + l15] =
                    fmaxf(acc[m][nf][j], 0.f);
}

extern "C" void kernel_launch(void* const* d_in, const int* in_sizes, int n_in,
                              void* d_out, int out_size, void* d_ws, size_t ws_size,
                              hipStream_t stream)
{
    const float* query = (const float*)d_in[0];
    const float* key   = (const float*)d_in[1];
    const float* value = (const float*)d_in[2];
    const float* WK    = (const float*)d_in[3];
    const float* WQ    = (const float*)d_in[4];
    const float* WV    = (const float*)d_in[5];
    const float* Wt    = (const float*)d_in[6];
    float* out = (float*)d_out;

    char* ws = (char*)d_ws;
    u16*   wqb = (u16*)(ws);                                   //  4 MB [B][LQ][64] bf16
    u16*   wkb = (u16*)(ws + (4u << 20));                      //  4 MB [B][LK][64] bf16
    u16*   wvT = (u16*)(ws + (8u << 20));                      // 32 MB [B][512][LK] bf16
    u16*   t   = (u16*)(ws + (40u << 20));                     // 32 MB [LQ][B][512] bf16
    float* Rq  = (float*)(ws + (72u << 20));                   // 128 KB [B][LQ] f32
    float* ci  = (float*)(ws + (72u << 20) + (128u << 10));    // 128 KB [B][LK] f32
    u16*   WQb = (u16*)(ws + (72u << 20) + (256u << 10));      // 64 KB
    u16*   WKb = (u16*)(ws + (72u << 20) + (320u << 10));      // 64 KB
    u16*   WVb = (u16*)(ws + (72u << 20) + (384u << 10));      // 512 KB
    u16*   Wtb = (u16*)(ws + (72u << 20) + (896u << 10));      // 512 KB

    k_cvt<<<32, 256, 0, stream>>>(WQ, WQb, DKK * DD);
    k_cvt<<<32, 256, 0, stream>>>(WK, WKb, DKK * DD);
    k_cvt<<<256, 256, 0, stream>>>(WV, WVb, DD * DD);
    k_cvt<<<256, 256, 0, stream>>>(Wt, Wtb, DD * DD);

    k_projqk<<<dim3(LQ / 128, BB), 256, 0, stream>>>(query, WQb, wqb);
    k_projqk<<<dim3(LK / 128, BB), 256, 0, stream>>>(key, WKb, wkb);
    k_projv <<<dim3(LK / 128, 2, BB), 512, 0, stream>>>(value, WVb, wvT);

    k_expsum<<<dim3(LQ / 64, BB), 256, 0, stream>>>(wqb, wkb, nullptr, Rq, 0.f);
    k_expsum<<<dim3(LK / 64, BB), 256, 0, stream>>>(wkb, wqb, Rq, ci, EPSF);

    k_pv<<<512, 512, 0, stream>>>(query, wqb, wkb, wvT, Rq, ci, t);
    k_final<<<dim3(256, 2), 512, 0, stream>>>(t, Wtb, out);
}